// Round 2
// baseline (7167.416 us; speedup 1.0000x reference)
//
#include <hip/hip_runtime.h>
#include <cstdint>
#include <cstddef>

// MultiExpertImputer — fp32 routed baseline, v2 (workspace-safe).
// Router (fp32, exact, concat fused into A-load) -> top-2 compaction ->
// per-expert segmented GEMMs (fp32 vector FMA, 128x128x16 LDS tiles) ->
// LN/gate epilogues -> weighted atomic scatter.
// Expert pipeline is chunked over slot rows so the two ping-pong activation
// buffers always fit inside ws_size (adaptive CH, constant across calls ->
// graph-capture safe). No hipMemset*; init via kernels.

#define E_   8
#define B_   4096
#define D_   1024
#define H_   2048
#define TOPK 2
#define EPS_ 1e-5f
#define S_   (B_ * TOPK)   // 8192 assignment slots

#define TM 128
#define TN 128
#define TKK 16

// ---------------------------------------------------------------------------
// init: zero imputed [B,D] and the 64-int control block (cnt/fill/seg + pad)
// grid = B*D/4/256 blocks of 256
// ---------------------------------------------------------------------------
__global__ __launch_bounds__(256)
void init_kernel(float* __restrict__ imputed, int* __restrict__ ctrl)
{
    int idx = blockIdx.x * 256 + threadIdx.x;
    *(float4*)(imputed + (size_t)idx * 4) = make_float4(0.f, 0.f, 0.f, 0.f);
    if (blockIdx.x == 0 && threadIdx.x < 64) ctrl[threadIdx.x] = 0;
}

// ---------------------------------------------------------------------------
// Tiled fp32 GEMM:  C[r_local, n] = act(Arow @ W[K,N] + bias[n])
// MODE 0: dense rows c0..; A row = concat(S0[gr,:D], S1[gr,:D]) (router)
// MODE 1: expert-segmented; A row = S0[row_list[slot], :K]      (dpe1 gather)
// MODE 2: expert-segmented; A row = A[slot - c0, :K]            (chained)
// Output rows are chunk-local (slot - c0). Tiles outside the (segment ∩
// chunk) intersection exit early.
// ---------------------------------------------------------------------------
template<int ACT, int MODE>   // ACT: 0 none, 1 relu
__global__ __launch_bounds__(256)
void gemm_k(const float* __restrict__ A,
            const float* __restrict__ S0,
            const float* __restrict__ S1,
            const int*   __restrict__ row_list,
            const float* __restrict__ W,      // [E,K,N] (MODE!=0) or [K,N]
            const float* __restrict__ bias,   // [E,N] or [N]
            float*       __restrict__ C,      // chunk-local [CH, N]
            int K, int N,
            const int* __restrict__ seg, const int* __restrict__ cnt,
            int c0, int chunkM, int Mtot)
{
    int e = 0, lo, hi;
    if (MODE == 0) {
        lo = c0;
        hi = min(c0 + chunkM, Mtot);
    } else {
        e = blockIdx.z;
        int s0 = seg[e], s1 = s0 + cnt[e];
        lo = max(s0, c0);
        hi = min(s1, c0 + chunkM);
    }
    int Me = hi - lo;
    const int rt = blockIdx.y * TM;
    if (rt >= Me) return;
    const int n0 = blockIdx.x * TN;
    const int lbase = lo - c0;            // chunk-local row base

    const float* We = W + (size_t)e * K * N;
    const float* be = bias + (size_t)e * N;

    __shared__ float As[TM][TKK + 1];     // +1 pad: conflict-free column reads
    __shared__ float Bs[TKK][TN];

    const int t  = threadIdx.x;
    const int tr = t >> 4;                // 0..15
    const int tc = t & 15;                // 0..15

    const int a_row = t >> 2;             // 0..63
    const int a_col = (t & 3) * 4;
    const int b_row = t >> 5;             // 0..7
    const int b_col = (t & 31) * 4;

    float acc[2][2][4][4];
#pragma unroll
    for (int p = 0; p < 2; ++p)
#pragma unroll
        for (int q = 0; q < 2; ++q)
#pragma unroll
            for (int i = 0; i < 4; ++i)
#pragma unroll
                for (int j = 0; j < 4; ++j) acc[p][q][i][j] = 0.f;

    for (int k0 = 0; k0 < K; k0 += TKK) {
#pragma unroll
        for (int h = 0; h < 2; ++h) {
            int r = rt + a_row + h * 64;
            float4 v = make_float4(0.f, 0.f, 0.f, 0.f);
            if (r < Me) {
                int kc = k0 + a_col;
                const float* src;
                if (MODE == 0) {
                    int gr = lo + r;
                    src = (kc < D_) ? (S0 + (size_t)gr * D_ + kc)
                                    : (S1 + (size_t)gr * D_ + (kc - D_));
                } else if (MODE == 1) {
                    int tok = row_list[lo + r];
                    src = S0 + (size_t)tok * K + kc;
                } else {
                    src = A + (size_t)(lbase + r) * K + kc;
                }
                v = *(const float4*)src;
            }
            As[a_row + h * 64][a_col + 0] = v.x;
            As[a_row + h * 64][a_col + 1] = v.y;
            As[a_row + h * 64][a_col + 2] = v.z;
            As[a_row + h * 64][a_col + 3] = v.w;
        }
#pragma unroll
        for (int h = 0; h < 2; ++h) {
            int kr = b_row + h * 8;
            *(float4*)&Bs[kr][b_col] =
                *(const float4*)(We + (size_t)(k0 + kr) * N + n0 + b_col);
        }
        __syncthreads();
#pragma unroll
        for (int kk = 0; kk < TKK; ++kk) {
            float a0[4], a1[4], bb0[4], bb1[4];
#pragma unroll
            for (int i = 0; i < 4; ++i) {
                a0[i] = As[tr * 4 + i][kk];
                a1[i] = As[64 + tr * 4 + i][kk];
            }
#pragma unroll
            for (int j = 0; j < 4; ++j) {
                bb0[j] = Bs[kk][tc * 4 + j];
                bb1[j] = Bs[kk][64 + tc * 4 + j];
            }
#pragma unroll
            for (int i = 0; i < 4; ++i)
#pragma unroll
                for (int j = 0; j < 4; ++j) {
                    acc[0][0][i][j] += a0[i] * bb0[j];
                    acc[0][1][i][j] += a0[i] * bb1[j];
                    acc[1][0][i][j] += a1[i] * bb0[j];
                    acc[1][1][i][j] += a1[i] * bb1[j];
                }
        }
        __syncthreads();
    }

#pragma unroll
    for (int p = 0; p < 2; ++p)
#pragma unroll
        for (int i = 0; i < 4; ++i) {
            int r = rt + p * 64 + tr * 4 + i;
            if (r >= Me) continue;
            size_t rowoff = (size_t)(lbase + r) * N;
#pragma unroll
            for (int q = 0; q < 2; ++q) {
                int col = n0 + q * 64 + tc * 4;
                float4 v;
                v.x = acc[p][q][i][0] + be[col + 0];
                v.y = acc[p][q][i][1] + be[col + 1];
                v.z = acc[p][q][i][2] + be[col + 2];
                v.w = acc[p][q][i][3] + be[col + 3];
                if (ACT == 1) {
                    v.x = fmaxf(v.x, 0.f); v.y = fmaxf(v.y, 0.f);
                    v.z = fmaxf(v.z, 0.f); v.w = fmaxf(v.w, 0.f);
                }
                *(float4*)&C[rowoff + col] = v;
            }
        }
}

// ---------------------------------------------------------------------------
// Router stage 2: scores = rh @ r_W2 + b2, softmax, top-2.
// rh is chunk-local (rows c0..). One wave per token.
// ---------------------------------------------------------------------------
__global__ __launch_bounds__(256)
void router_topk(const float* __restrict__ rh, const float* __restrict__ W2,
                 const float* __restrict__ b2,
                 float* __restrict__ sparse, int* __restrict__ topi,
                 float* __restrict__ topw, int* __restrict__ cnt, int c0)
{
    int wv = threadIdx.x >> 6, lane = threadIdx.x & 63;
    int bl = blockIdx.x * 4 + wv;         // chunk-local token
    int b  = c0 + bl;                     // global token
    const float* row = rh + (size_t)bl * H_;
    float acc[E_];
#pragma unroll
    for (int e = 0; e < E_; ++e) acc[e] = 0.f;
    for (int h = lane; h < H_; h += 64) {
        float v = row[h];
        const float* wp = W2 + (size_t)h * E_;
#pragma unroll
        for (int e = 0; e < E_; ++e) acc[e] += v * wp[e];
    }
#pragma unroll
    for (int e = 0; e < E_; ++e) {
        float s = acc[e];
#pragma unroll
        for (int off = 32; off > 0; off >>= 1) s += __shfl_down(s, off);
        acc[e] = s;
    }
    if (lane == 0) {
        float sc[E_];
#pragma unroll
        for (int e = 0; e < E_; ++e) sc[e] = acc[e] + b2[e];
        float m = sc[0];
#pragma unroll
        for (int e = 1; e < E_; ++e) m = fmaxf(m, sc[e]);
        float wgt[E_]; float sum = 0.f;
#pragma unroll
        for (int e = 0; e < E_; ++e) { wgt[e] = expf(sc[e] - m); sum += wgt[e]; }
        float inv = 1.f / sum;
#pragma unroll
        for (int e = 0; e < E_; ++e) wgt[e] *= inv;
        int i1 = 0;
#pragma unroll
        for (int e = 1; e < E_; ++e) if (wgt[e] > wgt[i1]) i1 = e;
        int i2 = (i1 == 0) ? 1 : 0;
#pragma unroll
        for (int e = 0; e < E_; ++e)
            if (e != i1 && wgt[e] > wgt[i2]) i2 = e;
#pragma unroll
        for (int e = 0; e < E_; ++e)
            sparse[(size_t)b * E_ + e] =
                (e == i1) ? wgt[i1] : ((e == i2) ? wgt[i2] : 0.f);
        topi[2 * b]     = i1; topw[2 * b]     = wgt[i1];
        topi[2 * b + 1] = i2; topw[2 * b + 1] = wgt[i2];
        atomicAdd(&cnt[i1], 1);
        atomicAdd(&cnt[i2], 1);
    }
}

__global__ void seg_scan(const int* __restrict__ cnt, int* __restrict__ seg)
{
    if (threadIdx.x == 0 && blockIdx.x == 0) {
        int s = 0;
        for (int e = 0; e < E_; ++e) { seg[e] = s; s += cnt[e]; }
    }
}

__global__ __launch_bounds__(256)
void fill_assign(const int* __restrict__ topi, const float* __restrict__ topw,
                 const int* __restrict__ seg, int* __restrict__ fill,
                 int* __restrict__ atok, int* __restrict__ ae,
                 float* __restrict__ aw)
{
    int b = blockIdx.x * 256 + threadIdx.x;
#pragma unroll
    for (int k = 0; k < TOPK; ++k) {
        int e = topi[2 * b + k];
        int slot = atomicAdd(&fill[e], 1);
        int i = seg[e] + slot;
        atok[i] = b; ae[i] = e; aw[i] = topw[2 * b + k];
    }
}

// ---------------------------------------------------------------------------
__device__ inline float block_sum256(float v, float* red)
{
#pragma unroll
    for (int off = 32; off > 0; off >>= 1) v += __shfl_down(v, off);
    int lane = threadIdx.x & 63, wv = threadIdx.x >> 6;
    if (lane == 0) red[wv] = v;
    __syncthreads();
    float tot = red[0] + red[1] + red[2] + red[3];
    __syncthreads();
    return tot;
}

// ---------------------------------------------------------------------------
// pos = LN(t + de); fused = [ce | pos]   (one block per chunk-local slot)
// ---------------------------------------------------------------------------
__global__ __launch_bounds__(256)
void pos_ln_fused(const float* __restrict__ tbuf,
                  const float* __restrict__ de, const float* __restrict__ ce,
                  const float* __restrict__ ln_g, const float* __restrict__ ln_b,
                  const int* __restrict__ atok, const int* __restrict__ ae,
                  float* __restrict__ fused, int c0)
{
    __shared__ float red[4];
    int i = blockIdx.x;                  // chunk-local
    int slot = c0 + i;
    int tok = atok[slot], e = ae[slot];
    int j = threadIdx.x * 4;
    float4 tv = *(const float4*)(tbuf + (size_t)i * D_ + j);
    float4 dv = *(const float4*)(de + (size_t)tok * D_ + j);
    float x0 = tv.x + dv.x, x1 = tv.y + dv.y, x2 = tv.z + dv.z, x3 = tv.w + dv.w;
    float mu = block_sum256(x0 + x1 + x2 + x3, red) * (1.f / D_);
    float d0 = x0 - mu, d1 = x1 - mu, d2 = x2 - mu, d3 = x3 - mu;
    float var = block_sum256(d0 * d0 + d1 * d1 + d2 * d2 + d3 * d3, red) * (1.f / D_);
    float rr = rsqrtf(var + EPS_);
    const float* g = ln_g + (size_t)e * D_ + j;
    const float* bb = ln_b + (size_t)e * D_ + j;
    float4 pos;
    pos.x = g[0] * d0 * rr + bb[0];
    pos.y = g[1] * d1 * rr + bb[1];
    pos.z = g[2] * d2 * rr + bb[2];
    pos.w = g[3] * d3 * rr + bb[3];
    *(float4*)(fused + (size_t)i * 2 * D_ + D_ + j) = pos;
    *(float4*)(fused + (size_t)i * 2 * D_ + j) =
        *(const float4*)(ce + (size_t)tok * D_ + j);
}

// ---------------------------------------------------------------------------
// gate = sigmoid(g_row . gate_W2[e] + gate_b2[e])   (one wave per slot)
// ---------------------------------------------------------------------------
__global__ __launch_bounds__(256)
void gate_kernel(const float* __restrict__ g, const float* __restrict__ W2,
                 const float* __restrict__ b2, const int* __restrict__ ae,
                 float* __restrict__ gateval, int c0)
{
    int wv = threadIdx.x >> 6, lane = threadIdx.x & 63;
    int i = blockIdx.x * 4 + wv;          // chunk-local
    int slot = c0 + i;
    int e = ae[slot];
    const float* row = g + (size_t)i * H_;
    const float* wp = W2 + (size_t)e * H_;
    float s = 0.f;
    for (int h = lane; h < H_; h += 64) s += row[h] * wp[h];
#pragma unroll
    for (int off = 32; off > 0; off >>= 1) s += __shfl_down(s, off);
    if (lane == 0) {
        float z = s + b2[e];
        gateval[slot] = 1.f / (1.f + expf(-z));
    }
}

// ---------------------------------------------------------------------------
// expert_out = LN(gate*cand + (1-gate)*ce); imputed[tok] += w * expert_out
// ---------------------------------------------------------------------------
__global__ __launch_bounds__(256)
void final_kernel(const float* __restrict__ cand, const float* __restrict__ ce,
                  const float* __restrict__ gateval,
                  const float* __restrict__ ln_g, const float* __restrict__ ln_b,
                  const int* __restrict__ atok, const int* __restrict__ ae,
                  const float* __restrict__ aw,
                  float* __restrict__ imputed, int c0)
{
    __shared__ float red[4];
    int i = blockIdx.x;                   // chunk-local
    int slot = c0 + i;
    int tok = atok[slot], e = ae[slot];
    float w = aw[slot], gv = gateval[slot];
    int j = threadIdx.x * 4;
    float4 cv = *(const float4*)(cand + (size_t)i * D_ + j);
    float4 ev = *(const float4*)(ce + (size_t)tok * D_ + j);
    float y0 = gv * cv.x + (1.f - gv) * ev.x;
    float y1 = gv * cv.y + (1.f - gv) * ev.y;
    float y2 = gv * cv.z + (1.f - gv) * ev.z;
    float y3 = gv * cv.w + (1.f - gv) * ev.w;
    float mu = block_sum256(y0 + y1 + y2 + y3, red) * (1.f / D_);
    float d0 = y0 - mu, d1 = y1 - mu, d2 = y2 - mu, d3 = y3 - mu;
    float var = block_sum256(d0 * d0 + d1 * d1 + d2 * d2 + d3 * d3, red) * (1.f / D_);
    float rr = rsqrtf(var + EPS_);
    const float* g = ln_g + (size_t)e * D_ + j;
    const float* bb = ln_b + (size_t)e * D_ + j;
    float* outp = imputed + (size_t)tok * D_ + j;
    atomicAdd(outp + 0, w * (g[0] * d0 * rr + bb[0]));
    atomicAdd(outp + 1, w * (g[1] * d1 * rr + bb[1]));
    atomicAdd(outp + 2, w * (g[2] * d2 * rr + bb[2]));
    atomicAdd(outp + 3, w * (g[3] * d3 * rr + bb[3]));
}

// ---------------------------------------------------------------------------
extern "C" void kernel_launch(void* const* d_in, const int* in_sizes, int n_in,
                              void* d_out, int out_size, void* d_ws, size_t ws_size,
                              hipStream_t stream)
{
    (void)in_sizes; (void)n_in; (void)out_size;

    const float* de       = (const float*)d_in[0];
    const float* ce       = (const float*)d_in[1];
    const float* dpe_W1   = (const float*)d_in[2];
    const float* dpe_b1   = (const float*)d_in[3];
    const float* dpe_W2   = (const float*)d_in[4];
    const float* dpe_b2   = (const float*)d_in[5];
    const float* dpe_W3   = (const float*)d_in[6];
    const float* dpe_b3   = (const float*)d_in[7];
    const float* dpe_Wo   = (const float*)d_in[8];
    const float* dpe_bo   = (const float*)d_in[9];
    const float* dpe_ln_g = (const float*)d_in[10];
    const float* dpe_ln_b = (const float*)d_in[11];
    const float* fus_W1   = (const float*)d_in[12];
    const float* fus_b1   = (const float*)d_in[13];
    const float* fus_W2   = (const float*)d_in[14];
    const float* fus_b2   = (const float*)d_in[15];
    const float* gate_W1  = (const float*)d_in[16];
    const float* gate_b1  = (const float*)d_in[17];
    const float* gate_W2  = (const float*)d_in[18];
    const float* gate_b2  = (const float*)d_in[19];
    const float* ln2_g    = (const float*)d_in[20];
    const float* ln2_b    = (const float*)d_in[21];
    const float* r_W1     = (const float*)d_in[22];
    const float* r_b1     = (const float*)d_in[23];
    const float* r_W2     = (const float*)d_in[24];
    const float* r_b2     = (const float*)d_in[25];

    char* ws = (char*)d_ws;
    // control block: cnt[0..7], fill[8..15], seg[16..23], pad to 64 ints
    int*   ctrl  = (int*)ws;
    int*   cnt   = ctrl;
    int*   fill  = ctrl + 8;
    int*   seg   = ctrl + 16;
    int*   atok  = (int*)(ws + 1024);         // [S_]
    int*   ae    = atok + S_;                 // [S_]
    float* aw    = (float*)(ae + S_);         // [S_]
    int*   topi  = (int*)(aw + S_);           // [2*B == S_]
    float* topw  = (float*)(topi + S_);       // [S_]
    float* gatev = topw + S_;                 // [S_]
    const size_t small_bytes = 256 * 1024;    // actual use ~197 KiB

    // Adaptive chunk: largest power-of-two CH (multiple of TM) whose two
    // CH x 2048 fp32 ping-pong buffers fit in ws_size. Constant across calls.
    int CH = 8192;
    while (CH > 128 &&
           small_bytes + (size_t)2 * CH * 2048 * sizeof(float) > ws_size)
        CH >>= 1;
    float* bufA = (float*)(ws + small_bytes);
    float* bufB = bufA + (size_t)CH * 2048;

    float* imputed = (float*)d_out;                 // [B, D]
    float* sparse  = imputed + (size_t)B_ * D_;     // [B, E]

    // --- init: zero imputed + control block ---
    init_kernel<<<(B_ * D_ / 4) / 256, 256, 0, stream>>>(imputed, ctrl);

    // --- router (fp32 exact; concat fused into A-load) ---
    const int CHR = (CH < B_) ? CH : B_;
    for (int c0 = 0; c0 < B_; c0 += CHR) {
        gemm_k<1, 0><<<dim3(H_ / TN, CHR / TM, 1), 256, 0, stream>>>(
            nullptr, de, ce, nullptr, r_W1, r_b1, bufA, 2 * D_, H_,
            nullptr, nullptr, c0, CHR, B_);
        router_topk<<<CHR / 4, 256, 0, stream>>>(bufA, r_W2, r_b2,
                                                 sparse, topi, topw, cnt, c0);
    }
    seg_scan<<<1, 64, 0, stream>>>(cnt, seg);
    fill_assign<<<B_ / 256, 256, 0, stream>>>(topi, topw, seg, fill,
                                              atok, ae, aw);

    // --- expert pipeline, chunked over the S_ slots ---
    for (int c0 = 0; c0 < S_; c0 += CH) {
        dim3 g2(H_ / TN, CH / TM, E_);   // N = 2048 outputs
        dim3 g1(D_ / TN, CH / TM, E_);   // N = 1024 outputs

        gemm_k<1, 1><<<g2, 256, 0, stream>>>(nullptr, de, nullptr, atok,
            dpe_W1, dpe_b1, bufB, D_, H_, seg, cnt, c0, CH, 0);       // h1->B
        gemm_k<1, 2><<<g2, 256, 0, stream>>>(bufB, nullptr, nullptr, nullptr,
            dpe_W2, dpe_b2, bufA, H_, H_, seg, cnt, c0, CH, 0);       // h2->A
        gemm_k<1, 2><<<g2, 256, 0, stream>>>(bufA, nullptr, nullptr, nullptr,
            dpe_W3, dpe_b3, bufB, H_, H_, seg, cnt, c0, CH, 0);       // h3->B
        gemm_k<0, 2><<<g1, 256, 0, stream>>>(bufB, nullptr, nullptr, nullptr,
            dpe_Wo, dpe_bo, bufA, H_, D_, seg, cnt, c0, CH, 0);       // t ->A

        pos_ln_fused<<<CH, 256, 0, stream>>>(bufA, de, ce, dpe_ln_g, dpe_ln_b,
                                             atok, ae, bufB, c0);     // fused->B

        gemm_k<1, 2><<<g2, 256, 0, stream>>>(bufB, nullptr, nullptr, nullptr,
            gate_W1, gate_b1, bufA, 2 * D_, H_, seg, cnt, c0, CH, 0); // g->A
        gate_kernel<<<CH / 4, 256, 0, stream>>>(bufA, gate_W2, gate_b2,
                                                ae, gatev, c0);

        gemm_k<1, 2><<<g2, 256, 0, stream>>>(bufB, nullptr, nullptr, nullptr,
            fus_W1, fus_b1, bufA, 2 * D_, H_, seg, cnt, c0, CH, 0);   // c->A
        gemm_k<0, 2><<<g1, 256, 0, stream>>>(bufA, nullptr, nullptr, nullptr,
            fus_W2, fus_b2, bufB, H_, D_, seg, cnt, c0, CH, 0);       // cand->B

        final_kernel<<<CH, 256, 0, stream>>>(bufB, ce, gatev, ln2_g, ln2_b,
                                             atok, ae, aw, imputed, c0);
    }
}

// Round 3
// 2190.777 us; speedup vs baseline: 3.2716x; 3.2716x over previous
//
#include <hip/hip_runtime.h>
#include <cstdint>
#include <cstddef>

// MultiExpertImputer v3 — fp32 router + fp16 MFMA expert path.
// Router (fp32 exact, vector-FMA GEMM) -> top-2 compaction -> per-expert
// segmented fp16 MFMA GEMMs (128x128x32 tiles, global_load_lds staging,
// XOR-swizzled LDS) -> fp32-internal LN/gate epilogues -> weighted scatter.
// Weights transposed+converted to [E][N][K] fp16 in ws each call (~170us).
// Falls back to the verified v2 all-fp32 path if ws_size is too small
// (decision depends only on ws_size -> constant across calls, graph-safe).

#define E_   8
#define B_   4096
#define D_   1024
#define H_   2048
#define TOPK 2
#define EPS_ 1e-5f
#define S_   (B_ * TOPK)

typedef _Float16 f16;
typedef _Float16 f16x8 __attribute__((ext_vector_type(8)));
typedef _Float16 f16x4 __attribute__((ext_vector_type(4)));
typedef float    f32x4 __attribute__((ext_vector_type(4)));

// ===========================================================================
// common small kernels
// ===========================================================================
__global__ __launch_bounds__(256)
void init_kernel(float* __restrict__ imputed, int* __restrict__ ctrl)
{
    int idx = blockIdx.x * 256 + threadIdx.x;
    *(float4*)(imputed + (size_t)idx * 4) = make_float4(0.f, 0.f, 0.f, 0.f);
    if (blockIdx.x == 0 && threadIdx.x < 64) ctrl[threadIdx.x] = 0;
}

__global__ __launch_bounds__(256)
void cvt_f16(const float* __restrict__ in, f16* __restrict__ out)
{
    int idx = blockIdx.x * 256 + threadIdx.x;     // 4 elems each
    float4 v = *(const float4*)(in + (size_t)idx * 4);
    f16x4 o; o.x = (f16)v.x; o.y = (f16)v.y; o.z = (f16)v.z; o.w = (f16)v.w;
    *(f16x4*)(out + (size_t)idx * 4) = o;
}

// W [E][K][N] fp32 -> Wt [E][N][K] fp16.  grid (N/32, K/32, E)
__global__ __launch_bounds__(256)
void transpose_w(const float* __restrict__ W, f16* __restrict__ Wt,
                 int K, int N)
{
    __shared__ float tile[32][33];
    const float* Win = W + (size_t)blockIdx.z * K * N;
    f16* Wout = Wt + (size_t)blockIdx.z * N * K;
    int k0 = blockIdx.y * 32, n0 = blockIdx.x * 32;
    int r = threadIdx.x >> 3, c4 = (threadIdx.x & 7) * 4;
    float4 v = *(const float4*)(Win + (size_t)(k0 + r) * N + n0 + c4);
    tile[r][c4 + 0] = v.x; tile[r][c4 + 1] = v.y;
    tile[r][c4 + 2] = v.z; tile[r][c4 + 3] = v.w;
    __syncthreads();
    f16x4 o;
    o.x = (f16)tile[c4 + 0][r];
    o.y = (f16)tile[c4 + 1][r];
    o.z = (f16)tile[c4 + 2][r];
    o.w = (f16)tile[c4 + 3][r];
    *(f16x4*)(Wout + (size_t)(n0 + r) * K + k0 + c4) = o;
}

// ===========================================================================
// fp16 MFMA GEMM: C[r,n] = act(A[r,:] @ Wt[e][n,:]^T + bias[e][n])
// A fp16 [*,K] (chunk-local rows, or gathered via row_list), Wt fp16 [E][N][K]
// C fp16 chunk-local [CH][N].  128x128 tile, BK=32, 4 waves.
// LDS swizzle: 16B slot' = slot ^ ((row>>1)&3)  (2-way banks = free).
// ===========================================================================
#define BM 128
#define BN 128
#define BK 32

__device__ __forceinline__ void gload_lds16(const void* g, void* l)
{
    __builtin_amdgcn_global_load_lds(
        (const __attribute__((address_space(1))) uint32_t*)g,
        (__attribute__((address_space(3))) uint32_t*)l, 16, 0, 0);
}

template<int ACT, int GATHER>   // ACT: 0 none, 1 relu
__global__ __launch_bounds__(256)
void gemm_f16(const f16* __restrict__ A,
              const f16* __restrict__ Asrc,
              const int* __restrict__ row_list,
              const f16* __restrict__ Wt,     // [E][N][K]
              const float* __restrict__ bias, // [E][N]
              f16* __restrict__ C,            // [CH][N]
              int K, int N,
              const int* __restrict__ seg, const int* __restrict__ cnt,
              int c0, int chunkM)
{
    const int e = blockIdx.z;
    const int s0 = seg[e], s1 = s0 + cnt[e];
    const int lo = max(s0, c0), hi = min(s1, c0 + chunkM);
    const int Me = hi - lo;
    const int rt = blockIdx.y * BM;
    if (rt >= Me) return;
    const int n0 = blockIdx.x * BN;
    const int lbase = lo - c0;

    const f16* We = Wt + (size_t)e * N * K;

    __shared__ f16 As[BM * BK];   // swizzled [128][32]
    __shared__ f16 Bs[BN * BK];

    const int t = threadIdx.x;
    const int wid = t >> 6, lane = t & 63;
    const int wr = wid >> 1, wc = wid & 1;

    // staging geometry: each instr covers 16 rows (4 lanes/row)
    const int srow = lane >> 2;          // 0..15 within instr
    const int slot = lane & 3;           // 16B slot within 64B row

    f32x4 acc[4][4];
#pragma unroll
    for (int i = 0; i < 4; ++i)
#pragma unroll
        for (int j = 0; j < 4; ++j) acc[i][j] = (f32x4)0.f;

    const int ks = lane >> 4;                    // k-slot for fragments
    const int fswz = (lane >> 1) & 3;            // ((row)>>1)&3 == (lane>>1)&3

    for (int kk0 = 0; kk0 < K; kk0 += BK) {
        // ---- stage A (wave stages rows wid*32 .. +31) ----
#pragma unroll
        for (int h = 0; h < 2; ++h) {
            int rowb = wid * 32 + h * 16;
            int row  = rowb + srow;
            int scol = kk0 + ((slot ^ ((row >> 1) & 3)) << 3);
            int rti  = rt + row; if (rti >= Me) rti = Me - 1;
            const f16* src;
            if (GATHER) {
                int tok = row_list[lo + rti];
                src = Asrc + (size_t)tok * K + scol;
            } else {
                src = A + (size_t)(lbase + rti) * K + scol;
            }
            gload_lds16(src, (char*)As + rowb * 64);
        }
        // ---- stage B (Wt rows n0+wid*32 .. +31) ----
#pragma unroll
        for (int h = 0; h < 2; ++h) {
            int rowb = wid * 32 + h * 16;
            int row  = rowb + srow;
            int scol = kk0 + ((slot ^ ((row >> 1) & 3)) << 3);
            const f16* src = We + (size_t)(n0 + row) * K + scol;
            gload_lds16(src, (char*)Bs + rowb * 64);
        }
        __syncthreads();

        f16x8 a[4], b[4];
#pragma unroll
        for (int fm = 0; fm < 4; ++fm) {
            int row = wr * 64 + fm * 16 + (lane & 15);
            a[fm] = *(const f16x8*)(As + row * 32 + ((ks ^ fswz) << 3));
        }
#pragma unroll
        for (int fn = 0; fn < 4; ++fn) {
            int row = wc * 64 + fn * 16 + (lane & 15);
            b[fn] = *(const f16x8*)(Bs + row * 32 + ((ks ^ fswz) << 3));
        }
#pragma unroll
        for (int fm = 0; fm < 4; ++fm)
#pragma unroll
            for (int fn = 0; fn < 4; ++fn)
                acc[fm][fn] = __builtin_amdgcn_mfma_f32_16x16x32_f16(
                    a[fm], b[fn], acc[fm][fn], 0, 0, 0);
        __syncthreads();
    }

    // ---- epilogue: bias + act + cvt + store ----
    float bn[4];
#pragma unroll
    for (int fn = 0; fn < 4; ++fn)
        bn[fn] = bias[(size_t)e * N + n0 + wc * 64 + fn * 16 + (lane & 15)];

#pragma unroll
    for (int fm = 0; fm < 4; ++fm) {
#pragma unroll
        for (int j = 0; j < 4; ++j) {
            int m = rt + wr * 64 + fm * 16 + (lane >> 4) * 4 + j;
            if (m >= Me) continue;
            size_t rowoff = (size_t)(lbase + m) * N;
#pragma unroll
            for (int fn = 0; fn < 4; ++fn) {
                int n = n0 + wc * 64 + fn * 16 + (lane & 15);
                float v = acc[fm][fn][j] + bn[fn];
                if (ACT == 1) v = fmaxf(v, 0.f);
                C[rowoff + n] = (f16)v;
            }
        }
    }
}

// ===========================================================================
// fp32 tiled GEMM (router + fallback path) — identical to verified v2
// ===========================================================================
#define TM 128
#define TN 128
#define TKK 16

template<int ACT, int MODE>   // MODE 0: dense concat(de,ce); 1: gather; 2: chained
__global__ __launch_bounds__(256)
void gemm_k(const float* __restrict__ A,
            const float* __restrict__ S0,
            const float* __restrict__ S1,
            const int*   __restrict__ row_list,
            const float* __restrict__ W,
            const float* __restrict__ bias,
            float*       __restrict__ C,
            int K, int N,
            const int* __restrict__ seg, const int* __restrict__ cnt,
            int c0, int chunkM, int Mtot)
{
    int e = 0, lo, hi;
    if (MODE == 0) {
        lo = c0; hi = min(c0 + chunkM, Mtot);
    } else {
        e = blockIdx.z;
        int s0 = seg[e], s1 = s0 + cnt[e];
        lo = max(s0, c0); hi = min(s1, c0 + chunkM);
    }
    int Me = hi - lo;
    const int rt = blockIdx.y * TM;
    if (rt >= Me) return;
    const int n0 = blockIdx.x * TN;
    const int lbase = lo - c0;

    const float* We = W + (size_t)e * K * N;
    const float* be = bias + (size_t)e * N;

    __shared__ float Asd[TM][TKK + 1];
    __shared__ float Bsd[TKK][TN];

    const int t  = threadIdx.x;
    const int tr = t >> 4;
    const int tc = t & 15;
    const int a_row = t >> 2;
    const int a_col = (t & 3) * 4;
    const int b_row = t >> 5;
    const int b_col = (t & 31) * 4;

    float acc[2][2][4][4];
#pragma unroll
    for (int p = 0; p < 2; ++p)
#pragma unroll
        for (int q = 0; q < 2; ++q)
#pragma unroll
            for (int i = 0; i < 4; ++i)
#pragma unroll
                for (int j = 0; j < 4; ++j) acc[p][q][i][j] = 0.f;

    for (int k0 = 0; k0 < K; k0 += TKK) {
#pragma unroll
        for (int h = 0; h < 2; ++h) {
            int r = rt + a_row + h * 64;
            float4 v = make_float4(0.f, 0.f, 0.f, 0.f);
            if (r < Me) {
                int kc = k0 + a_col;
                const float* src;
                if (MODE == 0) {
                    int gr = lo + r;
                    src = (kc < D_) ? (S0 + (size_t)gr * D_ + kc)
                                    : (S1 + (size_t)gr * D_ + (kc - D_));
                } else if (MODE == 1) {
                    int tok = row_list[lo + r];
                    src = S0 + (size_t)tok * K + kc;
                } else {
                    src = A + (size_t)(lbase + r) * K + kc;
                }
                v = *(const float4*)src;
            }
            Asd[a_row + h * 64][a_col + 0] = v.x;
            Asd[a_row + h * 64][a_col + 1] = v.y;
            Asd[a_row + h * 64][a_col + 2] = v.z;
            Asd[a_row + h * 64][a_col + 3] = v.w;
        }
#pragma unroll
        for (int h = 0; h < 2; ++h) {
            int kr = b_row + h * 8;
            *(float4*)&Bsd[kr][b_col] =
                *(const float4*)(We + (size_t)(k0 + kr) * N + n0 + b_col);
        }
        __syncthreads();
#pragma unroll
        for (int kk = 0; kk < TKK; ++kk) {
            float a0[4], a1[4], bb0[4], bb1[4];
#pragma unroll
            for (int i = 0; i < 4; ++i) {
                a0[i] = Asd[tr * 4 + i][kk];
                a1[i] = Asd[64 + tr * 4 + i][kk];
            }
#pragma unroll
            for (int j = 0; j < 4; ++j) {
                bb0[j] = Bsd[kk][tc * 4 + j];
                bb1[j] = Bsd[kk][64 + tc * 4 + j];
            }
#pragma unroll
            for (int i = 0; i < 4; ++i)
#pragma unroll
                for (int j = 0; j < 4; ++j) {
                    acc[0][0][i][j] += a0[i] * bb0[j];
                    acc[0][1][i][j] += a0[i] * bb1[j];
                    acc[1][0][i][j] += a1[i] * bb0[j];
                    acc[1][1][i][j] += a1[i] * bb1[j];
                }
        }
        __syncthreads();
    }

#pragma unroll
    for (int p = 0; p < 2; ++p)
#pragma unroll
        for (int i = 0; i < 4; ++i) {
            int r = rt + p * 64 + tr * 4 + i;
            if (r >= Me) continue;
            size_t rowoff = (size_t)(lbase + r) * N;
#pragma unroll
            for (int q = 0; q < 2; ++q) {
                int col = n0 + q * 64 + tc * 4;
                float4 v;
                v.x = acc[p][q][i][0] + be[col + 0];
                v.y = acc[p][q][i][1] + be[col + 1];
                v.z = acc[p][q][i][2] + be[col + 2];
                v.w = acc[p][q][i][3] + be[col + 3];
                if (ACT == 1) {
                    v.x = fmaxf(v.x, 0.f); v.y = fmaxf(v.y, 0.f);
                    v.z = fmaxf(v.z, 0.f); v.w = fmaxf(v.w, 0.f);
                }
                *(float4*)&C[rowoff + col] = v;
            }
        }
}

// ===========================================================================
// router stage 2 + compaction  (unchanged, verified)
// ===========================================================================
__global__ __launch_bounds__(256)
void router_topk(const float* __restrict__ rh, const float* __restrict__ W2,
                 const float* __restrict__ b2,
                 float* __restrict__ sparse, int* __restrict__ topi,
                 float* __restrict__ topw, int* __restrict__ cnt, int c0)
{
    int wv = threadIdx.x >> 6, lane = threadIdx.x & 63;
    int bl = blockIdx.x * 4 + wv;
    int b  = c0 + bl;
    const float* row = rh + (size_t)bl * H_;
    float acc[E_];
#pragma unroll
    for (int e = 0; e < E_; ++e) acc[e] = 0.f;
    for (int h = lane; h < H_; h += 64) {
        float v = row[h];
        const float* wp = W2 + (size_t)h * E_;
#pragma unroll
        for (int e = 0; e < E_; ++e) acc[e] += v * wp[e];
    }
#pragma unroll
    for (int e = 0; e < E_; ++e) {
        float s = acc[e];
#pragma unroll
        for (int off = 32; off > 0; off >>= 1) s += __shfl_down(s, off);
        acc[e] = s;
    }
    if (lane == 0) {
        float sc[E_];
#pragma unroll
        for (int e = 0; e < E_; ++e) sc[e] = acc[e] + b2[e];
        float m = sc[0];
#pragma unroll
        for (int e = 1; e < E_; ++e) m = fmaxf(m, sc[e]);
        float wgt[E_]; float sum = 0.f;
#pragma unroll
        for (int e = 0; e < E_; ++e) { wgt[e] = expf(sc[e] - m); sum += wgt[e]; }
        float inv = 1.f / sum;
#pragma unroll
        for (int e = 0; e < E_; ++e) wgt[e] *= inv;
        int i1 = 0;
#pragma unroll
        for (int e = 1; e < E_; ++e) if (wgt[e] > wgt[i1]) i1 = e;
        int i2 = (i1 == 0) ? 1 : 0;
#pragma unroll
        for (int e = 0; e < E_; ++e)
            if (e != i1 && wgt[e] > wgt[i2]) i2 = e;
#pragma unroll
        for (int e = 0; e < E_; ++e)
            sparse[(size_t)b * E_ + e] =
                (e == i1) ? wgt[i1] : ((e == i2) ? wgt[i2] : 0.f);
        topi[2 * b]     = i1; topw[2 * b]     = wgt[i1];
        topi[2 * b + 1] = i2; topw[2 * b + 1] = wgt[i2];
        atomicAdd(&cnt[i1], 1);
        atomicAdd(&cnt[i2], 1);
    }
}

__global__ void seg_scan(const int* __restrict__ cnt, int* __restrict__ seg)
{
    if (threadIdx.x == 0 && blockIdx.x == 0) {
        int s = 0;
        for (int e = 0; e < E_; ++e) { seg[e] = s; s += cnt[e]; }
    }
}

__global__ __launch_bounds__(256)
void fill_assign(const int* __restrict__ topi, const float* __restrict__ topw,
                 const int* __restrict__ seg, int* __restrict__ fill,
                 int* __restrict__ atok, int* __restrict__ ae,
                 float* __restrict__ aw)
{
    int b = blockIdx.x * 256 + threadIdx.x;
#pragma unroll
    for (int k = 0; k < TOPK; ++k) {
        int e = topi[2 * b + k];
        int slot = atomicAdd(&fill[e], 1);
        int i = seg[e] + slot;
        atok[i] = b; ae[i] = e; aw[i] = topw[2 * b + k];
    }
}

// ===========================================================================
__device__ inline float block_sum256(float v, float* red)
{
#pragma unroll
    for (int off = 32; off > 0; off >>= 1) v += __shfl_down(v, off);
    int lane = threadIdx.x & 63, wv = threadIdx.x >> 6;
    if (lane == 0) red[wv] = v;
    __syncthreads();
    float tot = red[0] + red[1] + red[2] + red[3];
    __syncthreads();
    return tot;
}

// ===========================================================================
// fp16-activation epilogues
// ===========================================================================
__global__ __launch_bounds__(256)
void pos_ln_fused16(const f16* __restrict__ tbuf,           // [CH][D]
                    const float* __restrict__ de, const float* __restrict__ ce,
                    const float* __restrict__ ln_g, const float* __restrict__ ln_b,
                    const int* __restrict__ atok, const int* __restrict__ ae,
                    f16* __restrict__ fused, int c0)        // [CH][2D]
{
    __shared__ float red[4];
    int i = blockIdx.x;
    int slot = c0 + i;
    int tok = atok[slot], e = ae[slot];
    int j = threadIdx.x * 4;
    f16x4 tv = *(const f16x4*)(tbuf + (size_t)i * D_ + j);
    float4 dv = *(const float4*)(de + (size_t)tok * D_ + j);
    float x0 = (float)tv.x + dv.x, x1 = (float)tv.y + dv.y;
    float x2 = (float)tv.z + dv.z, x3 = (float)tv.w + dv.w;
    float mu = block_sum256(x0 + x1 + x2 + x3, red) * (1.f / D_);
    float d0 = x0 - mu, d1 = x1 - mu, d2 = x2 - mu, d3 = x3 - mu;
    float var = block_sum256(d0 * d0 + d1 * d1 + d2 * d2 + d3 * d3, red) * (1.f / D_);
    float rr = rsqrtf(var + EPS_);
    const float* g  = ln_g + (size_t)e * D_ + j;
    const float* bb = ln_b + (size_t)e * D_ + j;
    f16x4 pos;
    pos.x = (f16)(g[0] * d0 * rr + bb[0]);
    pos.y = (f16)(g[1] * d1 * rr + bb[1]);
    pos.z = (f16)(g[2] * d2 * rr + bb[2]);
    pos.w = (f16)(g[3] * d3 * rr + bb[3]);
    *(f16x4*)(fused + (size_t)i * 2 * D_ + D_ + j) = pos;
    float4 cv = *(const float4*)(ce + (size_t)tok * D_ + j);
    f16x4 ch; ch.x = (f16)cv.x; ch.y = (f16)cv.y; ch.z = (f16)cv.z; ch.w = (f16)cv.w;
    *(f16x4*)(fused + (size_t)i * 2 * D_ + j) = ch;
}

__global__ __launch_bounds__(256)
void gate_kernel16(const f16* __restrict__ g, const float* __restrict__ W2,
                   const float* __restrict__ b2, const int* __restrict__ ae,
                   float* __restrict__ gateval, int c0)
{
    int wv = threadIdx.x >> 6, lane = threadIdx.x & 63;
    int i = blockIdx.x * 4 + wv;
    int slot = c0 + i;
    int e = ae[slot];
    const f16* row = g + (size_t)i * H_;
    const float* wp = W2 + (size_t)e * H_;
    float s = 0.f;
    for (int h = lane; h < H_; h += 64) s += (float)row[h] * wp[h];
#pragma unroll
    for (int off = 32; off > 0; off >>= 1) s += __shfl_down(s, off);
    if (lane == 0) {
        float z = s + b2[e];
        gateval[slot] = 1.f / (1.f + expf(-z));
    }
}

__global__ __launch_bounds__(256)
void final_kernel16(const f16* __restrict__ cand,           // [CH][D]
                    const float* __restrict__ ce,
                    const float* __restrict__ gateval,
                    const float* __restrict__ ln_g, const float* __restrict__ ln_b,
                    const int* __restrict__ atok, const int* __restrict__ ae,
                    const float* __restrict__ aw,
                    float* __restrict__ imputed, int c0)
{
    __shared__ float red[4];
    int i = blockIdx.x;
    int slot = c0 + i;
    int tok = atok[slot], e = ae[slot];
    float w = aw[slot], gv = gateval[slot];
    int j = threadIdx.x * 4;
    f16x4 ch = *(const f16x4*)(cand + (size_t)i * D_ + j);
    float4 ev = *(const float4*)(ce + (size_t)tok * D_ + j);
    float y0 = gv * (float)ch.x + (1.f - gv) * ev.x;
    float y1 = gv * (float)ch.y + (1.f - gv) * ev.y;
    float y2 = gv * (float)ch.z + (1.f - gv) * ev.z;
    float y3 = gv * (float)ch.w + (1.f - gv) * ev.w;
    float mu = block_sum256(y0 + y1 + y2 + y3, red) * (1.f / D_);
    float d0 = y0 - mu, d1 = y1 - mu, d2 = y2 - mu, d3 = y3 - mu;
    float var = block_sum256(d0 * d0 + d1 * d1 + d2 * d2 + d3 * d3, red) * (1.f / D_);
    float rr = rsqrtf(var + EPS_);
    const float* g  = ln_g + (size_t)e * D_ + j;
    const float* bb = ln_b + (size_t)e * D_ + j;
    float* outp = imputed + (size_t)tok * D_ + j;
    atomicAdd(outp + 0, w * (g[0] * d0 * rr + bb[0]));
    atomicAdd(outp + 1, w * (g[1] * d1 * rr + bb[1]));
    atomicAdd(outp + 2, w * (g[2] * d2 * rr + bb[2]));
    atomicAdd(outp + 3, w * (g[3] * d3 * rr + bb[3]));
}

// ===========================================================================
// fp32 epilogues (fallback path, verified v2)
// ===========================================================================
__global__ __launch_bounds__(256)
void pos_ln_fused32(const float* __restrict__ tbuf,
                    const float* __restrict__ de, const float* __restrict__ ce,
                    const float* __restrict__ ln_g, const float* __restrict__ ln_b,
                    const int* __restrict__ atok, const int* __restrict__ ae,
                    float* __restrict__ fused, int c0)
{
    __shared__ float red[4];
    int i = blockIdx.x;
    int slot = c0 + i;
    int tok = atok[slot], e = ae[slot];
    int j = threadIdx.x * 4;
    float4 tv = *(const float4*)(tbuf + (size_t)i * D_ + j);
    float4 dv = *(const float4*)(de + (size_t)tok * D_ + j);
    float x0 = tv.x + dv.x, x1 = tv.y + dv.y, x2 = tv.z + dv.z, x3 = tv.w + dv.w;
    float mu = block_sum256(x0 + x1 + x2 + x3, red) * (1.f / D_);
    float d0 = x0 - mu, d1 = x1 - mu, d2 = x2 - mu, d3 = x3 - mu;
    float var = block_sum256(d0 * d0 + d1 * d1 + d2 * d2 + d3 * d3, red) * (1.f / D_);
    float rr = rsqrtf(var + EPS_);
    const float* g  = ln_g + (size_t)e * D_ + j;
    const float* bb = ln_b + (size_t)e * D_ + j;
    float4 pos;
    pos.x = g[0] * d0 * rr + bb[0];
    pos.y = g[1] * d1 * rr + bb[1];
    pos.z = g[2] * d2 * rr + bb[2];
    pos.w = g[3] * d3 * rr + bb[3];
    *(float4*)(fused + (size_t)i * 2 * D_ + D_ + j) = pos;
    *(float4*)(fused + (size_t)i * 2 * D_ + j) =
        *(const float4*)(ce + (size_t)tok * D_ + j);
}

__global__ __launch_bounds__(256)
void gate_kernel32(const float* __restrict__ g, const float* __restrict__ W2,
                   const float* __restrict__ b2, const int* __restrict__ ae,
                   float* __restrict__ gateval, int c0)
{
    int wv = threadIdx.x >> 6, lane = threadIdx.x & 63;
    int i = blockIdx.x * 4 + wv;
    int slot = c0 + i;
    int e = ae[slot];
    const float* row = g + (size_t)i * H_;
    const float* wp = W2 + (size_t)e * H_;
    float s = 0.f;
    for (int h = lane; h < H_; h += 64) s += row[h] * wp[h];
#pragma unroll
    for (int off = 32; off > 0; off >>= 1) s += __shfl_down(s, off);
    if (lane == 0) {
        float z = s + b2[e];
        gateval[slot] = 1.f / (1.f + expf(-z));
    }
}

__global__ __launch_bounds__(256)
void final_kernel32(const float* __restrict__ cand, const float* __restrict__ ce,
                    const float* __restrict__ gateval,
                    const float* __restrict__ ln_g, const float* __restrict__ ln_b,
                    const int* __restrict__ atok, const int* __restrict__ ae,
                    const float* __restrict__ aw,
                    float* __restrict__ imputed, int c0)
{
    __shared__ float red[4];
    int i = blockIdx.x;
    int slot = c0 + i;
    int tok = atok[slot], e = ae[slot];
    float w = aw[slot], gv = gateval[slot];
    int j = threadIdx.x * 4;
    float4 cv = *(const float4*)(cand + (size_t)i * D_ + j);
    float4 ev = *(const float4*)(ce + (size_t)tok * D_ + j);
    float y0 = gv * cv.x + (1.f - gv) * ev.x;
    float y1 = gv * cv.y + (1.f - gv) * ev.y;
    float y2 = gv * cv.z + (1.f - gv) * ev.z;
    float y3 = gv * cv.w + (1.f - gv) * ev.w;
    float mu = block_sum256(y0 + y1 + y2 + y3, red) * (1.f / D_);
    float d0 = y0 - mu, d1 = y1 - mu, d2 = y2 - mu, d3 = y3 - mu;
    float var = block_sum256(d0 * d0 + d1 * d1 + d2 * d2 + d3 * d3, red) * (1.f / D_);
    float rr = rsqrtf(var + EPS_);
    const float* g  = ln_g + (size_t)e * D_ + j;
    const float* bb = ln_b + (size_t)e * D_ + j;
    float* outp = imputed + (size_t)tok * D_ + j;
    atomicAdd(outp + 0, w * (g[0] * d0 * rr + bb[0]));
    atomicAdd(outp + 1, w * (g[1] * d1 * rr + bb[1]));
    atomicAdd(outp + 2, w * (g[2] * d2 * rr + bb[2]));
    atomicAdd(outp + 3, w * (g[3] * d3 * rr + bb[3]));
}

// ===========================================================================
extern "C" void kernel_launch(void* const* d_in, const int* in_sizes, int n_in,
                              void* d_out, int out_size, void* d_ws, size_t ws_size,
                              hipStream_t stream)
{
    (void)in_sizes; (void)n_in; (void)out_size;

    const float* de       = (const float*)d_in[0];
    const float* ce       = (const float*)d_in[1];
    const float* dpe_W1   = (const float*)d_in[2];
    const float* dpe_b1   = (const float*)d_in[3];
    const float* dpe_W2   = (const float*)d_in[4];
    const float* dpe_b2   = (const float*)d_in[5];
    const float* dpe_W3   = (const float*)d_in[6];
    const float* dpe_b3   = (const float*)d_in[7];
    const float* dpe_Wo   = (const float*)d_in[8];
    const float* dpe_bo   = (const float*)d_in[9];
    const float* dpe_ln_g = (const float*)d_in[10];
    const float* dpe_ln_b = (const float*)d_in[11];
    const float* fus_W1   = (const float*)d_in[12];
    const float* fus_b1   = (const float*)d_in[13];
    const float* fus_W2   = (const float*)d_in[14];
    const float* fus_b2   = (const float*)d_in[15];
    const float* gate_W1  = (const float*)d_in[16];
    const float* gate_b1  = (const float*)d_in[17];
    const float* gate_W2  = (const float*)d_in[18];
    const float* gate_b2  = (const float*)d_in[19];
    const float* ln2_g    = (const float*)d_in[20];
    const float* ln2_b    = (const float*)d_in[21];
    const float* r_W1     = (const float*)d_in[22];
    const float* r_b1     = (const float*)d_in[23];
    const float* r_W2     = (const float*)d_in[24];
    const float* r_b2     = (const float*)d_in[25];

    char* ws = (char*)d_ws;
    int*   ctrl  = (int*)ws;
    int*   cnt   = ctrl;
    int*   fill  = ctrl + 8;
    int*   seg   = ctrl + 16;
    int*   atok  = (int*)(ws + 1024);
    int*   ae    = atok + S_;
    float* aw    = (float*)(ae + S_);
    int*   topi  = (int*)(aw + S_);
    float* topw  = (float*)(topi + S_);
    float* gatev = topw + S_;
    const size_t small_bytes = 256 * 1024;

    float* imputed = (float*)d_out;
    float* sparse  = imputed + (size_t)B_ * D_;

    // ---- fp16-path workspace layout ----
    size_t off = small_bytes;
    f16* de16 = (f16*)(ws + off);  off += (size_t)B_ * D_ * 2;          // 8 MB
    f16* W1t  = (f16*)(ws + off);  off += (size_t)E_ * H_ * D_ * 2;     // 33.5
    f16* W2t  = (f16*)(ws + off);  off += (size_t)E_ * H_ * H_ * 2;     // 67
    f16* W3t  = (f16*)(ws + off);  off += (size_t)E_ * H_ * H_ * 2;     // 67
    f16* Wot  = (f16*)(ws + off);  off += (size_t)E_ * D_ * H_ * 2;     // 33.5
    f16* FW1t = (f16*)(ws + off);  off += (size_t)E_ * H_ * H_ * 2;     // 67
    f16* FW2t = (f16*)(ws + off);  off += (size_t)E_ * D_ * H_ * 2;     // 33.5
    f16* GW1t = (f16*)(ws + off);  off += (size_t)E_ * H_ * H_ * 2;     // 67
    const size_t fixed16 = off;

    // chunk size for fp16 path: act region = 2 * CH * 2048 * 2 bytes
    int CH = 8192;
    while (CH > 1024 && fixed16 + (size_t)CH * 8192 > ws_size) CH >>= 1;
    const bool use16 = (fixed16 + (size_t)CH * 8192 <= ws_size);

    if (use16) {
        f16* actX = (f16*)(ws + fixed16);
        f16* actY = actX + (size_t)CH * H_;
        float* rh = (float*)actX;                  // router fp32 scratch

        init_kernel<<<(B_ * D_ / 4) / 256, 256, 0, stream>>>(imputed, ctrl);

        // weight transpose+convert (per call; ~1.1 GB traffic)
        cvt_f16<<<(B_ * D_ / 4) / 256, 256, 0, stream>>>(de, de16);
        transpose_w<<<dim3(H_/32, D_/32, E_), 256, 0, stream>>>(dpe_W1, W1t, D_, H_);
        transpose_w<<<dim3(H_/32, H_/32, E_), 256, 0, stream>>>(dpe_W2, W2t, H_, H_);
        transpose_w<<<dim3(H_/32, H_/32, E_), 256, 0, stream>>>(dpe_W3, W3t, H_, H_);
        transpose_w<<<dim3(D_/32, H_/32, E_), 256, 0, stream>>>(dpe_Wo, Wot, H_, D_);
        transpose_w<<<dim3(H_/32, H_/32, E_), 256, 0, stream>>>(fus_W1, FW1t, H_, H_);
        transpose_w<<<dim3(D_/32, H_/32, E_), 256, 0, stream>>>(fus_W2, FW2t, H_, D_);
        transpose_w<<<dim3(H_/32, H_/32, E_), 256, 0, stream>>>(gate_W1, GW1t, H_, H_);

        // router (fp32 exact)
        const int CHR = (CH < B_) ? CH : B_;
        for (int c0 = 0; c0 < B_; c0 += CHR) {
            gemm_k<1, 0><<<dim3(H_ / TN, CHR / TM, 1), 256, 0, stream>>>(
                nullptr, de, ce, nullptr, r_W1, r_b1, rh, 2 * D_, H_,
                nullptr, nullptr, c0, CHR, B_);
            router_topk<<<CHR / 4, 256, 0, stream>>>(rh, r_W2, r_b2,
                                                     sparse, topi, topw, cnt, c0);
        }
        seg_scan<<<1, 64, 0, stream>>>(cnt, seg);
        fill_assign<<<B_ / 256, 256, 0, stream>>>(topi, topw, seg, fill,
                                                  atok, ae, aw);

        for (int c0 = 0; c0 < S_; c0 += CH) {
            dim3 g2(H_ / BN, CH / BM, E_);
            dim3 g1(D_ / BN, CH / BM, E_);

            gemm_f16<1, 1><<<g2, 256, 0, stream>>>(nullptr, de16, atok,
                W1t, dpe_b1, actX, D_, H_, seg, cnt, c0, CH);
            gemm_f16<1, 0><<<g2, 256, 0, stream>>>(actX, nullptr, nullptr,
                W2t, dpe_b2, actY, H_, H_, seg, cnt, c0, CH);
            gemm_f16<1, 0><<<g2, 256, 0, stream>>>(actY, nullptr, nullptr,
                W3t, dpe_b3, actX, H_, H_, seg, cnt, c0, CH);
            gemm_f16<0, 0><<<g1, 256, 0, stream>>>(actX, nullptr, nullptr,
                Wot, dpe_bo, actY, H_, D_, seg, cnt, c0, CH);

            pos_ln_fused16<<<CH, 256, 0, stream>>>(actY, de, ce,
                dpe_ln_g, dpe_ln_b, atok, ae, actX, c0);

            gemm_f16<1, 0><<<g2, 256, 0, stream>>>(actX, nullptr, nullptr,
                GW1t, gate_b1, actY, 2 * D_, H_, seg, cnt, c0, CH);
            gate_kernel16<<<CH / 4, 256, 0, stream>>>(actY, gate_W2, gate_b2,
                                                      ae, gatev, c0);

            gemm_f16<1, 0><<<g2, 256, 0, stream>>>(actX, nullptr, nullptr,
                FW1t, fus_b1, actY, 2 * D_, H_, seg, cnt, c0, CH);
            gemm_f16<0, 0><<<g1, 256, 0, stream>>>(actY, nullptr, nullptr,
                FW2t, fus_b2, actX, H_, D_, seg, cnt, c0, CH);

            final_kernel16<<<CH, 256, 0, stream>>>(actX, ce, gatev,
                ln2_g, ln2_b, atok, ae, aw, imputed, c0);
        }
        return;
    }

    // ---------------- fp32 fallback (verified v2 path) ----------------
    int CH32 = 8192;
    while (CH32 > 128 &&
           small_bytes + (size_t)2 * CH32 * 2048 * sizeof(float) > ws_size)
        CH32 >>= 1;
    float* bufA = (float*)(ws + small_bytes);
    float* bufB = bufA + (size_t)CH32 * 2048;

    init_kernel<<<(B_ * D_ / 4) / 256, 256, 0, stream>>>(imputed, ctrl);

    const int CHR = (CH32 < B_) ? CH32 : B_;
    for (int c0 = 0; c0 < B_; c0 += CHR) {
        gemm_k<1, 0><<<dim3(H_ / TN, CHR / TM, 1), 256, 0, stream>>>(
            nullptr, de, ce, nullptr, r_W1, r_b1, bufA, 2 * D_, H_,
            nullptr, nullptr, c0, CHR, B_);
        router_topk<<<CHR / 4, 256, 0, stream>>>(bufA, r_W2, r_b2,
                                                 sparse, topi, topw, cnt, c0);
    }
    seg_scan<<<1, 64, 0, stream>>>(cnt, seg);
    fill_assign<<<B_ / 256, 256, 0, stream>>>(topi, topw, seg, fill,
                                              atok, ae, aw);

    for (int c0 = 0; c0 < S_; c0 += CH32) {
        dim3 g2(H_ / TN, CH32 / TM, E_);
        dim3 g1(D_ / TN, CH32 / TM, E_);

        gemm_k<1, 1><<<g2, 256, 0, stream>>>(nullptr, de, nullptr, atok,
            dpe_W1, dpe_b1, bufB, D_, H_, seg, cnt, c0, CH32, 0);
        gemm_k<1, 2><<<g2, 256, 0, stream>>>(bufB, nullptr, nullptr, nullptr,
            dpe_W2, dpe_b2, bufA, H_, H_, seg, cnt, c0, CH32, 0);
        gemm_k<1, 2><<<g2, 256, 0, stream>>>(bufA, nullptr, nullptr, nullptr,
            dpe_W3, dpe_b3, bufB, H_, H_, seg, cnt, c0, CH32, 0);
        gemm_k<0, 2><<<g1, 256, 0, stream>>>(bufB, nullptr, nullptr, nullptr,
            dpe_Wo, dpe_bo, bufA, H_, D_, seg, cnt, c0, CH32, 0);

        pos_ln_fused32<<<CH32, 256, 0, stream>>>(bufA, de, ce, dpe_ln_g, dpe_ln_b,
                                                 atok, ae, bufB, c0);

        gemm_k<1, 2><<<g2, 256, 0, stream>>>(bufB, nullptr, nullptr, nullptr,
            gate_W1, gate_b1, bufA, 2 * D_, H_, seg, cnt, c0, CH32, 0);
        gate_kernel32<<<CH32 / 4, 256, 0, stream>>>(bufA, gate_W2, gate_b2,
                                                    ae, gatev, c0);

        gemm_k<1, 2><<<g2, 256, 0, stream>>>(bufB, nullptr, nullptr, nullptr,
            fus_W1, fus_b1, bufA, 2 * D_, H_, seg, cnt, c0, CH32, 0);
        gemm_k<0, 2><<<g1, 256, 0, stream>>>(bufA, nullptr, nullptr, nullptr,
            fus_W2, fus_b2, bufB, H_, D_, seg, cnt, c0, CH32, 0);

        final_kernel32<<<CH32, 256, 0, stream>>>(bufB, ce, gatev, ln2_g, ln2_b,
                                                 atok, ae, aw, imputed, c0);
    }
}